// Round 9
// baseline (138.723 us; speedup 1.0000x reference)
//
#include <hip/hip_runtime.h>
#include <math.h>

#define BATCH 8192
#define DIM 1024
#define NCLS 1000
#define NPAD 1024         // padded class rows for the bf16 center matrix
#define NPAIRS 499500.0f  // 1000*999/2
#define INTER_TILES 136   // 16*17/2 upper-triangle 64x64 tiles
#define MAXROWS 128       // max rows per class tracked (Poisson mean 8.2, max ~35)

typedef float  f32x4  __attribute__((ext_vector_type(4)));
typedef short  bf16x8 __attribute__((ext_vector_type(8)));

// ---------------- helpers ----------------

__device__ inline float waveAllReduceAdd(float x) {
  #pragma unroll
  for (int m = 32; m > 0; m >>= 1) x += __shfl_xor(x, m);
  return x;
}

// block (256 thr) reduce, broadcast; sm >= 8 floats
__device__ inline float blockReduce1(float x, float* sm) {
  x = waveAllReduceAdd(x);
  int lane = threadIdx.x & 63, wid = threadIdx.x >> 6;
  __syncthreads();
  if (lane == 0) sm[wid] = x;
  __syncthreads();
  return sm[0] + sm[1] + sm[2] + sm[3];
}

__device__ inline unsigned short f2bf(float f) {
  unsigned int u = __float_as_uint(f);
  u += 0x7FFFu + ((u >> 16) & 1u);  // RNE
  return (unsigned short)(u >> 16);
}

// async 16B/lane global->LDS DMA (per-wave). LDS dest = wave-uniform base +
// lane*16; global src is per-lane. Counted by the wave's vmcnt.
__device__ inline void gload_lds16(const float* g, float* l) {
  __builtin_amdgcn_global_load_lds(
      (const __attribute__((address_space(1))) void*)g,
      (__attribute__((address_space(3))) void*)l, 16, 0, 0);
}

// wave-level drain of this wave's outstanding vmem (incl. global_load_lds).
__device__ inline void waitvm0() {
  asm volatile("s_waitcnt vmcnt(0)" ::: "memory");
}

// compiler-level memory ordering fence (stops cross-iteration hoisting of the
// next DMA above this iteration's LDS reads).
__device__ inline void cfence() { asm volatile("" ::: "memory"); }

// ---------------- K1: fused center update + intra losses ---------------------
// Block c: label scan -> s_rows (L2 broadcast).
// Pass 1 (wave-per-row, wave-private LDS staging, NO block barriers): stage
// 4KB row via 4 DMAs, per-wave vmcnt drain, shfl-reduce norm -> s_iw[t],
// accumulate normalized row into per-wave full-width acc.
// One combine barrier -> momentum -> c_new: bf16 store + f32 in s_c4 + ||c||^2.
// Pass 2 (wave-per-row, zero barriers): streaming register reads with
// immediate FMA consumption -- clean row dot (L1/L2-hot, just streamed) and
// adv row dot+norm (cold HBM), distances via 1 + ||c||^2 - 2*inv*(x.c).
// Per-class private outputs (no atomics, no zeroing pass).

__global__ __launch_bounds__(256, 4)
void center_intra_kernel(const float* __restrict__ feats,
                         const float* __restrict__ featsa,
                         const float* __restrict__ centers,
                         const int* __restrict__ labels,
                         unsigned short* __restrict__ centers_bf,
                         float* __restrict__ sqn,
                         float* __restrict__ pclean,
                         float* __restrict__ padv) {
  __shared__ float  s_stage[4][DIM];   // 16KB: per-wave private row buffer
  __shared__ float4 s_accf[4][256];    // 16KB: per-wave partial centers
  __shared__ float4 s_c4[256];         // 4KB: c_new (f32) for pass-2 dots
  __shared__ float  s_iw[MAXROWS];
  __shared__ int    s_rows[MAXROWS];
  __shared__ int    s_cnt;
  __shared__ int    s_anynz;
  __shared__ float  sm[8];

  int c = blockIdx.x;   // 0..1023
  int tid = threadIdx.x;
  int lane = tid & 63, w = tid >> 6;
  int fi = tid;         // float4 slot for full-width ops

  if (c >= NCLS) {  // zero-pad rows so the MFMA tiles can load unguarded
    ((ushort4*)(centers_bf + (size_t)c * DIM))[fi] = make_ushort4(0, 0, 0, 0);
    return;
  }

  // ---- self-select rows of this class ----
  if (tid == 0) { s_cnt = 0; s_anynz = 0; }
  __syncthreads();
  #pragma unroll 4
  for (int j = tid; j < BATCH; j += 256) {
    if (labels[j] == c) {
      int p = atomicAdd(&s_cnt, 1);
      if (p < MAXROWS) s_rows[p] = j;
    }
  }
  __syncthreads();
  int n = min(s_cnt, MAXROWS);

  // ---- pass 1: wave-per-row accumulation, no block barriers ----
  float4 acc[4];
  #pragma unroll
  for (int i = 0; i < 4; ++i) acc[i] = make_float4(0.f, 0.f, 0.f, 0.f);
  float* myst = s_stage[w];

  for (int t = w; t < n; t += 4) {
    int r = s_rows[t];
    const float* src = feats + (size_t)r * DIM;
    #pragma unroll
    for (int q = 0; q < 4; ++q)
      gload_lds16(src + q * 256 + lane * 4, myst + q * 256);
    waitvm0();  // wave-level: this wave's 4KB row has landed in its slice
    float4 v[4];
    #pragma unroll
    for (int i = 0; i < 4; ++i) v[i] = ((const float4*)myst)[lane + 64 * i];
    float ss = 0.f;
    #pragma unroll
    for (int i = 0; i < 4; ++i)
      ss += v[i].x * v[i].x + v[i].y * v[i].y + v[i].z * v[i].z + v[i].w * v[i].w;
    ss = waveAllReduceAdd(ss);
    float iw = 1.0f / fmaxf(sqrtf(ss), 1e-12f);
    if (lane == 0) s_iw[t] = iw;   // read back only by this same wave
    #pragma unroll
    for (int i = 0; i < 4; ++i) {
      acc[i].x += v[i].x * iw; acc[i].y += v[i].y * iw;
      acc[i].z += v[i].z * iw; acc[i].w += v[i].w * iw;
    }
    cfence();  // next iteration's DMA must not hoist above these LDS reads
  }

  // ---- one combine barrier -> momentum -> store ----
  #pragma unroll
  for (int i = 0; i < 4; ++i) s_accf[w][lane + 64 * i] = acc[i];
  float4 cv = ((const float4*)(centers + (size_t)c * DIM))[fi];
  if (cv.x != 0.f || cv.y != 0.f || cv.z != 0.f || cv.w != 0.f) s_anynz = 1;
  __syncthreads();
  float4 a0 = s_accf[0][fi], a1 = s_accf[1][fi], a2 = s_accf[2][fi], a3 = s_accf[3][fi];
  float4 sum = make_float4(a0.x + a1.x + a2.x + a3.x, a0.y + a1.y + a2.y + a3.y,
                           a0.z + a1.z + a2.z + a3.z, a0.w + a1.w + a2.w + a3.w);

  float invc = 1.0f / fmaxf((float)n, 1.0f);
  float4 mean = make_float4(sum.x * invc, sum.y * invc, sum.z * invc, sum.w * invc);

  float4 o;
  if (s_anynz) {
    o = make_float4(0.9f * cv.x + 0.1f * mean.x, 0.9f * cv.y + 0.1f * mean.y,
                    0.9f * cv.z + 0.1f * mean.z, 0.9f * cv.w + 0.1f * mean.w);
  } else {
    o = mean;
  }
  if (n == 0) o = cv;

  ((ushort4*)(centers_bf + (size_t)c * DIM))[fi] =
      make_ushort4(f2bf(o.x), f2bf(o.y), f2bf(o.z), f2bf(o.w));
  s_c4[fi] = o;  // made visible to all waves by blockReduce1's first barrier

  float sq = blockReduce1(o.x * o.x + o.y * o.y + o.z * o.z + o.w * o.w, sm);
  if (tid == 0) sqn[c] = sq;

  // ---- pass 2: intra distances, streaming reg reads, zero barriers ----
  float sumc = 0.f, suma = 0.f;
  for (int t = w; t < n; t += 4) {
    int r = s_rows[t];
    const float4* rp = (const float4*)(feats  + (size_t)r * DIM);  // L1/L2-hot
    const float4* ap = (const float4*)(featsa + (size_t)r * DIM);  // cold HBM
    float dotf = 0.f, dota = 0.f, ssa = 0.f;
    #pragma unroll
    for (int i = 0; i < 4; ++i) {
      float4 vf = rp[lane + 64 * i];
      float4 va = ap[lane + 64 * i];
      float4 cc = s_c4[lane + 64 * i];
      dotf += vf.x * cc.x + vf.y * cc.y + vf.z * cc.z + vf.w * cc.w;
      dota += va.x * cc.x + va.y * cc.y + va.z * cc.z + va.w * cc.w;
      ssa  += va.x * va.x + va.y * va.y + va.z * va.z + va.w * va.w;
    }
    dotf = waveAllReduceAdd(dotf);
    dota = waveAllReduceAdd(dota);
    ssa  = waveAllReduceAdd(ssa);
    if (lane == 0) {
      float iw = s_iw[t];
      float inva = 1.0f / fmaxf(sqrtf(ssa), 1e-12f);
      float d2c = 1.0f + sq - 2.0f * iw * dotf;
      float d2a = 1.0f + sq - 2.0f * inva * dota;
      sumc += sqrtf(fmaxf(d2c, 0.0f));
      suma += sqrtf(fmaxf(d2a, 0.0f));
    }
  }

  float totc = blockReduce1(sumc, sm);  // only lane0s carry nonzero
  float tota = blockReduce1(suma, sm);
  if (tid == 0) { pclean[c] = totc; padv[c] = tota; }
}

// ---------------- K2: inter loss, 136 upper-triangle 64x64 MFMA tiles --------

__global__ __launch_bounds__(256, 4)
void inter_mfma_kernel(const unsigned short* __restrict__ Cbf,
                       const float* __restrict__ sq,
                       float* __restrict__ pinter) {
  __shared__ float smr[8];
  int tid = threadIdx.x;  // 256
  int bid = blockIdx.x;   // 0..135

  int t = bid;
  int bi = 0;
  while (t >= 16 - bi) { t -= 16 - bi; ++bi; }
  int bj = bi + t;  // bi <= bj, upper triangle of 16x16 tile grid

  int w = tid >> 6;
  int wy = w >> 1, wx = w & 1;
  int lane = tid & 63;
  int m = lane & 15;
  int q = lane >> 4;

  int i0 = bi * 64 + wy * 32;
  int j0 = bj * 64 + wx * 32;

  const unsigned short* arow0 = Cbf + (size_t)(i0 + m) * DIM;
  const unsigned short* arow1 = Cbf + (size_t)(i0 + 16 + m) * DIM;
  const unsigned short* brow0 = Cbf + (size_t)(j0 + m) * DIM;
  const unsigned short* brow1 = Cbf + (size_t)(j0 + 16 + m) * DIM;

  f32x4 acc00 = {0.f, 0.f, 0.f, 0.f}, acc01 = acc00, acc10 = acc00, acc11 = acc00;

  #pragma unroll 4
  for (int k0 = 0; k0 < DIM; k0 += 32) {
    int ko = k0 + q * 8;
    bf16x8 a0 = *(const bf16x8*)(arow0 + ko);
    bf16x8 a1 = *(const bf16x8*)(arow1 + ko);
    bf16x8 b0 = *(const bf16x8*)(brow0 + ko);
    bf16x8 b1 = *(const bf16x8*)(brow1 + ko);
    acc00 = __builtin_amdgcn_mfma_f32_16x16x32_bf16(a0, b0, acc00, 0, 0, 0);
    acc01 = __builtin_amdgcn_mfma_f32_16x16x32_bf16(a0, b1, acc01, 0, 0, 0);
    acc10 = __builtin_amdgcn_mfma_f32_16x16x32_bf16(a1, b0, acc10, 0, 0, 0);
    acc11 = __builtin_amdgcn_mfma_f32_16x16x32_bf16(a1, b1, acc11, 0, 0, 0);
  }

  float local = 0.f;
  int colA = lane & 15;
  int rbase = (lane >> 4) * 4;
  #pragma unroll
  for (int si = 0; si < 2; ++si) {
    #pragma unroll
    for (int sj = 0; sj < 2; ++sj) {
      f32x4 a = (si == 0) ? (sj == 0 ? acc00 : acc01) : (sj == 0 ? acc10 : acc11);
      #pragma unroll
      for (int r = 0; r < 4; ++r) {
        int i = i0 + si * 16 + rbase + r;
        int j = j0 + sj * 16 + colA;
        if (j < NCLS && i < j) {
          float d2 = sq[i] + sq[j] - 2.0f * a[r];
          float d = sqrtf(fmaxf(d2, 0.0f));
          local += fmaxf(1.0f - d, 0.0f);
        }
      }
    }
  }
  float tot = blockReduce1(local, smr);
  if (tid == 0) pinter[bid] = tot;  // private slot, no atomic, no zeroing
}

// ---------------- K3: final combine ----------------

__global__ void final_kernel(const float* __restrict__ pclean,
                             const float* __restrict__ padv,
                             const float* __restrict__ pinter,
                             float* __restrict__ out) {
  __shared__ float sm[8];
  int t = threadIdx.x;  // 256
  float ci = 0.f;
  for (int i = t; i < NCLS; i += 256) ci += pclean[i] + padv[i];
  float e = (t < INTER_TILES) ? pinter[t] : 0.f;
  ci = blockReduce1(ci, sm);
  e = blockReduce1(e, sm);
  if (t == 0) {
    float intra = ci * (1.0f / (float)BATCH);
    float inter = e / NPAIRS;
    out[0] = intra - 0.5f * inter;  // LAMBDA_INTRA=1, LAMBDA_INTER=0.5
  }
}

// ---------------- launch ----------------

extern "C" void kernel_launch(void* const* d_in, const int* in_sizes, int n_in,
                              void* d_out, int out_size, void* d_ws, size_t ws_size,
                              hipStream_t stream) {
  const float* features     = (const float*)d_in[0];
  const float* features_adv = (const float*)d_in[1];
  const float* centers      = (const float*)d_in[2];
  const int*   labels       = (const int*)d_in[3];
  float* out = (float*)d_out;

  // ws layout: centers_bf[1024*1024 u16] | sqn[1024 f] | pclean[1024 f] |
  //            padv[1024 f] | pinter[256 f]
  unsigned short* centers_bf = (unsigned short*)d_ws;
  float* sqn = (float*)(centers_bf + (size_t)NPAD * DIM);
  float* pclean = sqn + 1024;
  float* padv = pclean + 1024;
  float* pinter = padv + 1024;

  hipLaunchKernelGGL(center_intra_kernel, dim3(NPAD), dim3(256), 0, stream,
                     features, features_adv, centers, labels, centers_bf, sqn,
                     pclean, padv);
  hipLaunchKernelGGL(inter_mfma_kernel, dim3(INTER_TILES), dim3(256), 0, stream,
                     centers_bf, sqn, pinter);
  hipLaunchKernelGGL(final_kernel, dim3(1), dim3(256), 0, stream, pclean, padv,
                     pinter, out);
}

// Round 10
// 134.307 us; speedup vs baseline: 1.0329x; 1.0329x over previous
//
#include <hip/hip_runtime.h>
#include <math.h>

#define BATCH 8192
#define DIM 1024
#define NCLS 1000
#define NPAD 1024         // padded class rows for the bf16 center matrix
#define NPAIRS 499500.0f  // 1000*999/2
#define INTER_TILES 136   // 16*17/2 upper-triangle 64x64 tiles
#define MAXROWS 128       // max rows per class tracked (Poisson mean 8.2, max ~35)

typedef float  f32x4  __attribute__((ext_vector_type(4)));
typedef short  bf16x8 __attribute__((ext_vector_type(8)));

// ---------------- helpers ----------------

__device__ inline float waveAllReduceAdd(float x) {
  #pragma unroll
  for (int m = 32; m > 0; m >>= 1) x += __shfl_xor(x, m);
  return x;
}

// block (256 thr) reduce, broadcast; sm >= 8 floats
__device__ inline float blockReduce1(float x, float* sm) {
  x = waveAllReduceAdd(x);
  int lane = threadIdx.x & 63, wid = threadIdx.x >> 6;
  __syncthreads();
  if (lane == 0) sm[wid] = x;
  __syncthreads();
  return sm[0] + sm[1] + sm[2] + sm[3];
}

__device__ inline unsigned short f2bf(float f) {
  unsigned int u = __float_as_uint(f);
  u += 0x7FFFu + ((u >> 16) & 1u);  // RNE
  return (unsigned short)(u >> 16);
}

// async 16B/lane global->LDS DMA (per-wave). LDS dest = wave-uniform base +
// lane*16; global src is per-lane. Counted by the wave's vmcnt.
__device__ inline void gload_lds16(const float* g, float* l) {
  __builtin_amdgcn_global_load_lds(
      (const __attribute__((address_space(1))) void*)g,
      (__attribute__((address_space(3))) void*)l, 16, 0, 0);
}

__device__ inline void waitvm0() {
  asm volatile("s_waitcnt vmcnt(0)" ::: "memory");
}
// counted wait: drain all but the newest 4 vmem ops (the in-flight prefetch)
__device__ inline void waitvm4() {
  asm volatile("s_waitcnt vmcnt(4)" ::: "memory");
}
// compiler-level memory ordering fence (pins issue order of vmem ops).
__device__ inline void cfence() { asm volatile("" ::: "memory"); }

// ---------------- K1: fused center update + intra, double-buffered DMA -------
// Block c: label scan -> s_rows. Wave w owns rows w, w+4, ... with TWO private
// 4KB LDS buffers (s_stage[2w], s_stage[2w+1]).
// Pass 1 (no block barriers): prefetch row t+4 via DMA, waitcnt vmcnt(4)
// (drains row t only), norm-reduce + accumulate row t from LDS. HBM latency
// hides under the previous row's compute.
// Combine (staging area reused for the cross-wave partial exchange) ->
// momentum -> c_new: bf16 store + f32 in s_c4 + ||c||^2.
// Pass 2 (no block barriers): feats row t register-loads (L2-hot) issued
// BEFORE the fa(t+4) prefetch DMAs, so vmcnt(4) drains {fa(t), feats(t)} and
// leaves fa(t+4) in flight. Distances via 1 + ||c||^2 - 2*inv*(x.c).

__global__ __launch_bounds__(256, 4)
void center_intra_kernel(const float* __restrict__ feats,
                         const float* __restrict__ featsa,
                         const float* __restrict__ centers,
                         const int* __restrict__ labels,
                         unsigned short* __restrict__ centers_bf,
                         float* __restrict__ sqn,
                         float* __restrict__ pclean,
                         float* __restrict__ padv) {
  __shared__ float  s_stage[8][DIM];   // 32KB: 2 buffers per wave; combine area
  __shared__ float4 s_c4[256];         // 4KB: c_new (f32) for pass-2 dots
  __shared__ float  s_iw[MAXROWS];
  __shared__ int    s_rows[MAXROWS];
  __shared__ int    s_cnt;
  __shared__ int    s_anynz;
  __shared__ float  sm[8];

  int c = blockIdx.x;   // 0..1023
  int tid = threadIdx.x;
  int lane = tid & 63, w = tid >> 6;
  int fi = tid;         // float4 slot for full-width ops

  if (c >= NCLS) {  // zero-pad rows so the MFMA tiles can load unguarded
    ((ushort4*)(centers_bf + (size_t)c * DIM))[fi] = make_ushort4(0, 0, 0, 0);
    return;
  }

  // ---- self-select rows of this class (int4 label scan, L2 broadcast) ----
  if (tid == 0) { s_cnt = 0; s_anynz = 0; }
  __syncthreads();
  const int4* lab4 = (const int4*)labels;
  #pragma unroll 2
  for (int j = tid; j < BATCH / 4; j += 256) {
    int4 lv = lab4[j];
    if (lv.x == c) { int p = atomicAdd(&s_cnt, 1); if (p < MAXROWS) s_rows[p] = 4 * j; }
    if (lv.y == c) { int p = atomicAdd(&s_cnt, 1); if (p < MAXROWS) s_rows[p] = 4 * j + 1; }
    if (lv.z == c) { int p = atomicAdd(&s_cnt, 1); if (p < MAXROWS) s_rows[p] = 4 * j + 2; }
    if (lv.w == c) { int p = atomicAdd(&s_cnt, 1); if (p < MAXROWS) s_rows[p] = 4 * j + 3; }
  }
  __syncthreads();
  int n = min(s_cnt, MAXROWS);

  float* bufA = s_stage[2 * w];
  float* bufB = s_stage[2 * w + 1];

  // ---- pass 1: wave-per-row, double-buffered DMA, no block barriers ----
  float4 acc[4];
  #pragma unroll
  for (int i = 0; i < 4; ++i) acc[i] = make_float4(0.f, 0.f, 0.f, 0.f);

  if (w < n) {  // prologue: prefetch first owned row
    const float* src = feats + (size_t)s_rows[w] * DIM;
    #pragma unroll
    for (int q = 0; q < 4; ++q) gload_lds16(src + q * 256 + lane * 4, bufA + q * 256);
  }
  for (int t = w; t < n; t += 4) {
    int tn = t + 4;
    if (tn < n) {  // prefetch next row into the other buffer
      const float* src = feats + (size_t)s_rows[tn] * DIM;
      #pragma unroll
      for (int q = 0; q < 4; ++q) gload_lds16(src + q * 256 + lane * 4, bufB + q * 256);
      cfence();
      waitvm4();   // drain row t's 4 DMAs; leave row tn's in flight
    } else {
      waitvm0();
    }
    float4 v[4];
    #pragma unroll
    for (int i = 0; i < 4; ++i) v[i] = ((const float4*)bufA)[lane + 64 * i];
    float ss = 0.f;
    #pragma unroll
    for (int i = 0; i < 4; ++i)
      ss += v[i].x * v[i].x + v[i].y * v[i].y + v[i].z * v[i].z + v[i].w * v[i].w;
    ss = waveAllReduceAdd(ss);
    float iw = 1.0f / fmaxf(sqrtf(ss), 1e-12f);
    if (lane == 0) s_iw[t] = iw;   // read back only by this same wave
    #pragma unroll
    for (int i = 0; i < 4; ++i) {
      acc[i].x += v[i].x * iw; acc[i].y += v[i].y * iw;
      acc[i].z += v[i].z * iw; acc[i].w += v[i].w * iw;
    }
    cfence();
    float* tmp = bufA; bufA = bufB; bufB = tmp;
  }

  // ---- combine (reuse staging area), momentum, store ----
  __syncthreads();  // all waves done reading their buffers
  #pragma unroll
  for (int i = 0; i < 4; ++i) ((float4*)s_stage[w])[lane + 64 * i] = acc[i];
  float4 cv = ((const float4*)(centers + (size_t)c * DIM))[fi];
  if (cv.x != 0.f || cv.y != 0.f || cv.z != 0.f || cv.w != 0.f) s_anynz = 1;
  __syncthreads();
  float4 a0 = ((const float4*)s_stage[0])[fi], a1 = ((const float4*)s_stage[1])[fi];
  float4 a2 = ((const float4*)s_stage[2])[fi], a3 = ((const float4*)s_stage[3])[fi];
  float4 sum = make_float4(a0.x + a1.x + a2.x + a3.x, a0.y + a1.y + a2.y + a3.y,
                           a0.z + a1.z + a2.z + a3.z, a0.w + a1.w + a2.w + a3.w);

  float invc = 1.0f / fmaxf((float)n, 1.0f);
  float4 mean = make_float4(sum.x * invc, sum.y * invc, sum.z * invc, sum.w * invc);

  float4 o;
  if (s_anynz) {
    o = make_float4(0.9f * cv.x + 0.1f * mean.x, 0.9f * cv.y + 0.1f * mean.y,
                    0.9f * cv.z + 0.1f * mean.z, 0.9f * cv.w + 0.1f * mean.w);
  } else {
    o = mean;
  }
  if (n == 0) o = cv;

  ((ushort4*)(centers_bf + (size_t)c * DIM))[fi] =
      make_ushort4(f2bf(o.x), f2bf(o.y), f2bf(o.z), f2bf(o.w));
  s_c4[fi] = o;  // visible to all waves via blockReduce1's barriers

  float sq = blockReduce1(o.x * o.x + o.y * o.y + o.z * o.z + o.w * o.w, sm);
  if (tid == 0) sqn[c] = sq;
  // blockReduce1's barriers also fence the combine reads from pass-2 DMAs

  // ---- pass 2: intra distances, double-buffered fa DMA, no barriers ----
  bufA = s_stage[2 * w];
  bufB = s_stage[2 * w + 1];
  float sumc = 0.f, suma = 0.f;

  if (w < n) {  // prologue: prefetch first fa row
    const float* src = featsa + (size_t)s_rows[w] * DIM;
    #pragma unroll
    for (int q = 0; q < 4; ++q) gload_lds16(src + q * 256 + lane * 4, bufA + q * 256);
  }
  for (int t = w; t < n; t += 4) {
    int r = s_rows[t];
    // feats row (L2-hot) register loads FIRST -> drained by the vmcnt(4)
    const float4* rp = (const float4*)(feats + (size_t)r * DIM);
    float4 vf[4];
    #pragma unroll
    for (int i = 0; i < 4; ++i) vf[i] = rp[lane + 64 * i];
    cfence();
    int tn = t + 4;
    if (tn < n) {  // prefetch next fa row into the other buffer
      const float* src = featsa + (size_t)s_rows[tn] * DIM;
      #pragma unroll
      for (int q = 0; q < 4; ++q) gload_lds16(src + q * 256 + lane * 4, bufB + q * 256);
      cfence();
      waitvm4();   // drain fa(t) + feats(t); leave fa(tn) in flight
    } else {
      waitvm0();
    }
    float dotf = 0.f, dota = 0.f, ssa = 0.f;
    #pragma unroll
    for (int i = 0; i < 4; ++i) {
      float4 va = ((const float4*)bufA)[lane + 64 * i];
      float4 cc = s_c4[lane + 64 * i];
      dotf += vf[i].x * cc.x + vf[i].y * cc.y + vf[i].z * cc.z + vf[i].w * cc.w;
      dota += va.x * cc.x + va.y * cc.y + va.z * cc.z + va.w * cc.w;
      ssa  += va.x * va.x + va.y * va.y + va.z * va.z + va.w * va.w;
    }
    dotf = waveAllReduceAdd(dotf);
    dota = waveAllReduceAdd(dota);
    ssa  = waveAllReduceAdd(ssa);
    if (lane == 0) {
      float iw = s_iw[t];
      float inva = 1.0f / fmaxf(sqrtf(ssa), 1e-12f);
      float d2c = 1.0f + sq - 2.0f * iw * dotf;
      float d2a = 1.0f + sq - 2.0f * inva * dota;
      sumc += sqrtf(fmaxf(d2c, 0.0f));
      suma += sqrtf(fmaxf(d2a, 0.0f));
    }
    cfence();
    float* tmp = bufA; bufA = bufB; bufB = tmp;
  }

  float totc = blockReduce1(sumc, sm);  // only lane0s carry nonzero
  float tota = blockReduce1(suma, sm);
  if (tid == 0) { pclean[c] = totc; padv[c] = tota; }
}

// ---------------- K2: inter loss, 136 upper-triangle 64x64 MFMA tiles --------

__global__ __launch_bounds__(256, 4)
void inter_mfma_kernel(const unsigned short* __restrict__ Cbf,
                       const float* __restrict__ sq,
                       float* __restrict__ pinter) {
  __shared__ float smr[8];
  int tid = threadIdx.x;  // 256
  int bid = blockIdx.x;   // 0..135

  int t = bid;
  int bi = 0;
  while (t >= 16 - bi) { t -= 16 - bi; ++bi; }
  int bj = bi + t;  // bi <= bj, upper triangle of 16x16 tile grid

  int w = tid >> 6;
  int wy = w >> 1, wx = w & 1;
  int lane = tid & 63;
  int m = lane & 15;
  int q = lane >> 4;

  int i0 = bi * 64 + wy * 32;
  int j0 = bj * 64 + wx * 32;

  const unsigned short* arow0 = Cbf + (size_t)(i0 + m) * DIM;
  const unsigned short* arow1 = Cbf + (size_t)(i0 + 16 + m) * DIM;
  const unsigned short* brow0 = Cbf + (size_t)(j0 + m) * DIM;
  const unsigned short* brow1 = Cbf + (size_t)(j0 + 16 + m) * DIM;

  f32x4 acc00 = {0.f, 0.f, 0.f, 0.f}, acc01 = acc00, acc10 = acc00, acc11 = acc00;

  #pragma unroll 4
  for (int k0 = 0; k0 < DIM; k0 += 32) {
    int ko = k0 + q * 8;
    bf16x8 a0 = *(const bf16x8*)(arow0 + ko);
    bf16x8 a1 = *(const bf16x8*)(arow1 + ko);
    bf16x8 b0 = *(const bf16x8*)(brow0 + ko);
    bf16x8 b1 = *(const bf16x8*)(brow1 + ko);
    acc00 = __builtin_amdgcn_mfma_f32_16x16x32_bf16(a0, b0, acc00, 0, 0, 0);
    acc01 = __builtin_amdgcn_mfma_f32_16x16x32_bf16(a0, b1, acc01, 0, 0, 0);
    acc10 = __builtin_amdgcn_mfma_f32_16x16x32_bf16(a1, b0, acc10, 0, 0, 0);
    acc11 = __builtin_amdgcn_mfma_f32_16x16x32_bf16(a1, b1, acc11, 0, 0, 0);
  }

  float local = 0.f;
  int colA = lane & 15;
  int rbase = (lane >> 4) * 4;
  #pragma unroll
  for (int si = 0; si < 2; ++si) {
    #pragma unroll
    for (int sj = 0; sj < 2; ++sj) {
      f32x4 a = (si == 0) ? (sj == 0 ? acc00 : acc01) : (sj == 0 ? acc10 : acc11);
      #pragma unroll
      for (int r = 0; r < 4; ++r) {
        int i = i0 + si * 16 + rbase + r;
        int j = j0 + sj * 16 + colA;
        if (j < NCLS && i < j) {
          float d2 = sq[i] + sq[j] - 2.0f * a[r];
          float d = sqrtf(fmaxf(d2, 0.0f));
          local += fmaxf(1.0f - d, 0.0f);
        }
      }
    }
  }
  float tot = blockReduce1(local, smr);
  if (tid == 0) pinter[bid] = tot;  // private slot, no atomic, no zeroing
}

// ---------------- K3: final combine ----------------

__global__ void final_kernel(const float* __restrict__ pclean,
                             const float* __restrict__ padv,
                             const float* __restrict__ pinter,
                             float* __restrict__ out) {
  __shared__ float sm[8];
  int t = threadIdx.x;  // 256
  float ci = 0.f;
  for (int i = t; i < NCLS; i += 256) ci += pclean[i] + padv[i];
  float e = (t < INTER_TILES) ? pinter[t] : 0.f;
  ci = blockReduce1(ci, sm);
  e = blockReduce1(e, sm);
  if (t == 0) {
    float intra = ci * (1.0f / (float)BATCH);
    float inter = e / NPAIRS;
    out[0] = intra - 0.5f * inter;  // LAMBDA_INTRA=1, LAMBDA_INTER=0.5
  }
}

// ---------------- launch ----------------

extern "C" void kernel_launch(void* const* d_in, const int* in_sizes, int n_in,
                              void* d_out, int out_size, void* d_ws, size_t ws_size,
                              hipStream_t stream) {
  const float* features     = (const float*)d_in[0];
  const float* features_adv = (const float*)d_in[1];
  const float* centers      = (const float*)d_in[2];
  const int*   labels       = (const int*)d_in[3];
  float* out = (float*)d_out;

  // ws layout: centers_bf[1024*1024 u16] | sqn[1024 f] | pclean[1024 f] |
  //            padv[1024 f] | pinter[256 f]
  unsigned short* centers_bf = (unsigned short*)d_ws;
  float* sqn = (float*)(centers_bf + (size_t)NPAD * DIM);
  float* pclean = sqn + 1024;
  float* padv = pclean + 1024;
  float* pinter = padv + 1024;

  hipLaunchKernelGGL(center_intra_kernel, dim3(NPAD), dim3(256), 0, stream,
                     features, features_adv, centers, labels, centers_bf, sqn,
                     pclean, padv);
  hipLaunchKernelGGL(inter_mfma_kernel, dim3(INTER_TILES), dim3(256), 0, stream,
                     centers_bf, sqn, pinter);
  hipLaunchKernelGGL(final_kernel, dim3(1), dim3(256), 0, stream, pclean, padv,
                     pinter, out);
}